// Round 10
// baseline (155.759 us; speedup 1.0000x reference)
//
#include <hip/hip_runtime.h>

// LSTM: B=65536 seqs, T=256, E=H=5, x in {0,1}. One thread per sequence.
// 1024 waves = 1 wave/SIMD. Measured model (R3/R5/R6/R7/R9):
//   v_exp/v_rcp ~16 cyc VALUBusy + ~13 cyc exposed latency each ->
//   31 trans ops ~= 900 of R7's 1115 wall cyc/step. Trans convoy kernel.
// R10: trans-free exp2, SCALAR-clean (R9's regression was pk<->scalar
//   v_mov churn inside the packed soft-exp, not the math):
//   sexp2(v) = { n=rndne(v); u=v-n; p=deg5poly(u); bits(p) += n<<23 }
//   = 9 full-rate instr, no v_exp, no final mul (exponent bit-add exact:
//   p in [0.707,1.414], |n| <= 60 via v_med3 clamp). Matvec stays packed
//   (v2f lanes ARE two scalar VGPRs -> extraction free); combine scalar.
//   Only 6 pair-grouped v_rcp remain transcendental.
// Math identical to R7 (passed):
//   c' = [chat*Ai*Ag + 2log2e*(Eg-1)*Af]/(Ai*Af*Ag),  A* = 1+E*
//   h  = (Ec-1)/((1+Eo)(1+Ec));  chat = 2log2e*c;  rcp pair-grouped
//   (products < ~2^70 on this data; float max 2^128).
// Gate-pair layout: p0..7: row=(p>>1)*5+(p&1)*2+h ->
//   (i0,i1)(i2,i3)(f0,f1)(f2,f3)(g0,g1)(g2,g3)(o0,o1)(o2,o3)
//   p8:(i4,f4)=rows{4,9}; p9:(g4,o4)=rows{14,19}

typedef float v2f __attribute__((ext_vector_type(2)));

constexpr int TT = 256;

__device__ __forceinline__ float frcp(float v)  { return __builtin_amdgcn_rcpf(v); }

// ---- full-rate scalar exp2: 9 instr, reassociation-immune ----
#define EXP2_C0 1.0f
#define EXP2_C1 6.931471805599453e-1f
#define EXP2_C2 2.402265069591007e-1f
#define EXP2_C3 5.550410866482158e-2f
#define EXP2_C4 9.618129107628477e-3f
#define EXP2_C5 1.3333558146428443e-3f

__device__ __forceinline__ float sexp2(float v) {
    float n = __builtin_rintf(v);        // v_rndne_f32
    float u = v - n;                     // exact, u in [-0.5, 0.5]
    int  ni = (int)n;                    // v_cvt_i32_f32
    float p = fmaf(EXP2_C5, u, EXP2_C4);
    p = fmaf(p, u, EXP2_C3);
    p = fmaf(p, u, EXP2_C2);
    p = fmaf(p, u, EXP2_C1);
    p = fmaf(p, u, EXP2_C0);             // p in [0.7071, 1.4143]
    int pb = __builtin_bit_cast(int, p) + (ni << 23);   // v_lshl_add_u32
    return __builtin_bit_cast(float, pb);
}

__device__ __forceinline__ int pair_row(int p, int h) {
    if (p < 8) return (p >> 1) * 5 + (p & 1) * 2 + h;
    return (p == 8) ? (h ? 9 : 4) : (h ? 19 : 14);
}

// pack two uniform floats into a uniform 64-bit value (SGPR pair residency)
__device__ __forceinline__ double upack(float w0, float w1) {
    unsigned lo = (unsigned)__builtin_amdgcn_readfirstlane(__builtin_bit_cast(int, w0));
    unsigned hi = (unsigned)__builtin_amdgcn_readfirstlane(__builtin_bit_cast(int, w1));
    unsigned long long u = ((unsigned long long)hi << 32) | lo;
    return __builtin_bit_cast(double, u);
}

__global__ __launch_bounds__(256)
__attribute__((amdgpu_waves_per_eu(1, 1)))
void lstm_fused(
    const int* __restrict__ x,       // [B, T]
    const float* __restrict__ emb,   // [2, E]
    const float* __restrict__ W_ih,  // [4H, E]
    const float* __restrict__ W_hh,  // [4H, H]
    const float* __restrict__ b_ih,  // [4H]
    const float* __restrict__ b_hh,  // [4H]
    const float* __restrict__ W_lin, // [2, H]
    const float* __restrict__ b_lin, // [2]
    float* __restrict__ out)         // [B, 2]
{
    const int b = blockIdx.x * blockDim.x + threadIdx.x;

    const float NL2E  = -1.4426950408889634f;  // -log2(e)   (sigmoid rows)
    const float T2L2E =  2.8853900817779268f;  // 2*log2(e)  (tanh rows)

    // ---- setup ----
    double wu[4][10];   // matvec weights k=0..3, uniform -> SGPR pairs
    v2f    wv[10];      // matvec weights k=4, pinned VGPR
    v2f bpk[10], dpk[10];
#pragma unroll
    for (int p = 0; p < 10; ++p) {
        float v0[2], v1[2], w4[2];
        float wk[4][2];
#pragma unroll
        for (int h = 0; h < 2; ++h) {
            const int r = pair_row(p, h);
            const float s = (r >= 10 && r < 15) ? T2L2E : NL2E;
            float g0 = b_ih[r] + b_hh[r], g1 = g0;
#pragma unroll
            for (int e = 0; e < 5; ++e) {
                float w = W_ih[r * 5 + e];
                g0 = fmaf(w, emb[e],     g0);
                g1 = fmaf(w, emb[5 + e], g1);
            }
            v0[h] = s * g0;
            v1[h] = s * (g1 - g0);
#pragma unroll
            for (int k = 0; k < 4; ++k) wk[k][h] = s * W_hh[r * 5 + k];
            w4[h] = s * W_hh[r * 5 + 4];
        }
#pragma unroll
        for (int k = 0; k < 4; ++k) wu[k][p] = upack(wk[k][0], wk[k][1]);
        asm volatile("" : "+v"(w4[0]), "+v"(w4[1]));
        wv[p][0] = w4[0]; wv[p][1] = w4[1];
        asm volatile("" : "+v"(v0[0]), "+v"(v0[1]), "+v"(v1[0]), "+v"(v1[1]));
        bpk[p][0] = v0[0]; bpk[p][1] = v0[1];
        dpk[p][0] = v1[0]; dpk[p][1] = v1[1];
    }

    float chat[5] = {0.f, 0.f, 0.f, 0.f, 0.f};
    float hh[5]   = {0.f, 0.f, 0.f, 0.f, 0.f};

    auto step = [&](int xt) {
        const float xtf = (float)xt;
        v2f xv; xv[0] = xtf; xv[1] = xtf;
        v2f g[10];
#pragma unroll
        for (int p = 0; p < 10; ++p)
            g[p] = __builtin_elementwise_fma(xv, dpk[p], bpk[p]);
        // ---- recurrent matvec (packed): k=0..3 SGPR pairs, k=4 VGPR ----
#pragma unroll
        for (int k = 0; k < 4; ++k) {
            v2f hv; hv[0] = hh[k]; hv[1] = hh[k];
#pragma unroll
            for (int p = 0; p < 10; ++p) {
                v2f w = __builtin_bit_cast(v2f, wu[k][p]);
                g[p] = __builtin_elementwise_fma(w, hv, g[p]);
            }
        }
        {
            v2f hv; hv[0] = hh[4]; hv[1] = hh[4];
#pragma unroll
            for (int p = 0; p < 10; ++p)
                g[p] = __builtin_elementwise_fma(wv[p], hv, g[p]);
        }

        // ---- scalar gate views (v2f lanes are plain VGPRs; free) ----
        const float Gi[5] = {g[0][0], g[0][1], g[1][0], g[1][1], g[8][0]};
        const float Gf[5] = {g[2][0], g[2][1], g[3][0], g[3][1], g[8][1]};
        const float Gg[5] = {g[4][0], g[4][1], g[5][0], g[5][1], g[9][0]};
        const float Go[5] = {g[6][0], g[6][1], g[7][0], g[7][1], g[9][1]};

        // ---- 20 gate exp2, all full-rate ----
        float Ei[5], Ef[5], Eg[5], Eo[5];
#pragma unroll
        for (int j = 0; j < 5; ++j) {
            Ei[j] = sexp2(Gi[j]);
            Ef[j] = sexp2(Gf[j]);
            Eg[j] = sexp2(Gg[j]);
            Eo[j] = sexp2(Go[j]);
        }

        // ---- c-phase: N/D, one shared denominator per unit ----
        float N[5], D[5];
#pragma unroll
        for (int j = 0; j < 5; ++j) {
            float Ai = 1.f + Ei[j], Af = 1.f + Ef[j], Ag = 1.f + Eg[j];
            float P  = Ai * Ag;
            D[j] = P * Af;
            float t = fmaf(T2L2E, Eg[j], -T2L2E);     // 2log2e*(Eg-1)
            N[j] = fmaf(chat[j], P, t * Af);
        }
        {   // paired reciprocals (3 rcp)
            float R01 = frcp(D[0] * D[1]);
            chat[0] = (N[0] * D[1]) * R01;
            chat[1] = (N[1] * D[0]) * R01;
            float R23 = frcp(D[2] * D[3]);
            chat[2] = (N[2] * D[3]) * R23;
            chat[3] = (N[3] * D[2]) * R23;
            chat[4] = N[4] * frcp(D[4]);
        }

        // ---- h-phase: Ec full-rate; h = (Ec-1)/((1+Eo)(1+Ec)) ----
        float Tn[5], Dn[5];
#pragma unroll
        for (int j = 0; j < 5; ++j) {
            // clamp for the exponent bit-add path (real |chat| <~ 35)
            float cc = fminf(fmaxf(chat[j], -60.f), 60.f);   // v_med3
            float Ec = sexp2(cc);
            Dn[j] = (1.f + Eo[j]) * (1.f + Ec);
            Tn[j] = Ec - 1.f;
        }
        {
            float S01 = frcp(Dn[0] * Dn[1]);
            hh[0] = (Tn[0] * Dn[1]) * S01;
            hh[1] = (Tn[1] * Dn[0]) * S01;
            float S23 = frcp(Dn[2] * Dn[3]);
            hh[2] = (Tn[2] * Dn[3]) * S23;
            hh[3] = (Tn[3] * Dn[2]) * S23;
            hh[4] = Tn[4] * frcp(Dn[4]);
        }
    };

    // ---- main scan: 64 int4 loads, prefetch-next, 4 steps per iter ----
    const int4* xr = reinterpret_cast<const int4*>(x + (size_t)b * TT);
    int4 cur = xr[0];
#pragma unroll 1
    for (int it = 0; it < TT / 4 - 1; ++it) {
        int4 nxt = xr[it + 1];
        step(cur.x); step(cur.y); step(cur.z); step(cur.w);
        cur = nxt;
    }
    step(cur.x); step(cur.y); step(cur.z); step(cur.w);

    // ---- linear head ----
    float o0 = b_lin[0], o1 = b_lin[1];
#pragma unroll
    for (int j = 0; j < 5; ++j) {
        o0 = fmaf(W_lin[j],     hh[j], o0);
        o1 = fmaf(W_lin[5 + j], hh[j], o1);
    }
    reinterpret_cast<float2*>(out)[b] = make_float2(o0, o1);
}

extern "C" void kernel_launch(void* const* d_in, const int* in_sizes, int n_in,
                              void* d_out, int out_size, void* d_ws, size_t ws_size,
                              hipStream_t stream) {
    const int* x        = (const int*)d_in[0];
    const float* emb    = (const float*)d_in[1];
    const float* W_ih   = (const float*)d_in[2];
    const float* W_hh   = (const float*)d_in[3];
    const float* b_ih   = (const float*)d_in[4];
    const float* b_hh   = (const float*)d_in[5];
    const float* W_lin  = (const float*)d_in[6];
    const float* b_lin  = (const float*)d_in[7];
    float* out          = (float*)d_out;

    const int B = in_sizes[0] / TT;   // 65536
    const int block = 256;
    const int grid = B / block;       // 256 blocks -> 1024 waves -> 1/SIMD

    lstm_fused<<<grid, block, 0, stream>>>(x, emb, W_ih, W_hh, b_ih, b_hh,
                                           W_lin, b_lin, out);
}

// Round 11
// 130.924 us; speedup vs baseline: 1.1897x; 1.1897x over previous
//
#include <hip/hip_runtime.h>

// LSTM: B=65536 seqs, T=256, E=H=5, x in {0,1}.
// FOUR lanes per sequence, one hidden UNIT per lane (+ unit 4 shared):
//   lane role j in {0..3} owns unit j's four gates (rows j, 5+j, 10+j, 15+j)
//   and additionally gate-type j of unit 4 (row 5j+4). Unit-4 combine is
//   computed redundantly by all 4 lanes from quad-broadcast E values.
// Why: 65536*4 threads = 4096 waves = EXACTLY 4 waves/SIMD (R7 had 1), so
//   dependency/trans latencies are hidden by co-resident waves -- the ~405
//   cyc/step stall pool measured on R7. Lane-ops are conserved (exp count
//   28/seq vs 25; rcp 8/seq vs 6). All cross-lane via DPP quad_perm
//   (full-rate, no LDS): no pswap role-select bloat that killed R5.
// Math identical to R7 (validated, absmax 4.9e-4):
//   c' = [chat*Ai*Ag + 2log2e*(Eg-1)*Af]/(Ai*Af*Ag),  A* = 1+E*
//   h  = (Ec-1)/((1+Eo)(1+Ec));  chat = 2log2e*c;  v_exp for all exps;
//   rcp shared between own-unit and unit-4 (product < ~2^70 on this data).

typedef float v2f __attribute__((ext_vector_type(2)));

constexpr int TT = 256;

__device__ __forceinline__ float fexp2(float v) { return __builtin_amdgcn_exp2f(v); }
__device__ __forceinline__ float frcp(float v)  { return __builtin_amdgcn_rcpf(v); }

// quad_perm broadcast: CTRL = 0x00/0x55/0xAA/0xFF -> lane 0/1/2/3 of each quad
template<int CTRL>
__device__ __forceinline__ float qb(float v) {
    return __builtin_bit_cast(float, __builtin_amdgcn_mov_dpp(
        __builtin_bit_cast(int, v), CTRL, 0xF, 0xF, true));
}

__global__ __launch_bounds__(256)
__attribute__((amdgpu_waves_per_eu(4)))
void lstm_q4(
    const int* __restrict__ x,       // [B, T]
    const float* __restrict__ emb,   // [2, E]
    const float* __restrict__ W_ih,  // [4H, E]
    const float* __restrict__ W_hh,  // [4H, H]
    const float* __restrict__ b_ih,  // [4H]
    const float* __restrict__ b_hh,  // [4H]
    const float* __restrict__ W_lin, // [2, H]
    const float* __restrict__ b_lin, // [2]
    float* __restrict__ out)         // [B, 2]
{
    const int tid  = blockIdx.x * blockDim.x + threadIdx.x;
    const int seq  = tid >> 2;
    const int role = tid & 3;

    const float NL2E  = -1.4426950408889634f;  // -log2(e)   (sigmoid rows)
    const float T2L2E =  2.8853900817779268f;  // 2*log2(e)  (tanh rows)

    // ---- per-lane weight gather (role-dependent data, role-uniform code) ----
    auto prep = [&](int r, float s, float& base, float& delta) {
        float g0 = b_ih[r] + b_hh[r], g1 = g0;
#pragma unroll
        for (int e = 0; e < 5; ++e) {
            float w = W_ih[r * 5 + e];
            g0 = fmaf(w, emb[e],     g0);
            g1 = fmaf(w, emb[5 + e], g1);
        }
        base  = s * g0;
        delta = s * (g1 - g0);
    };

    const int ri = role, rf = 5 + role, rg = 10 + role, ro = 15 + role;
    const int r4 = 5 * role + 4;                  // my gate-type of unit 4
    const float s4 = (role == 2) ? T2L2E : NL2E;  // row 14 is the tanh row

    v2f wif[5], wgo[5], bif, bgo, dif, dgo;
    float w4[5], b4, d4;
    {
        float bi, di, bf, df, bg, dg, bo, dq;
        prep(ri, NL2E,  bi, di);
        prep(rf, NL2E,  bf, df);
        prep(rg, T2L2E, bg, dg);
        prep(ro, NL2E,  bo, dq);
        prep(r4, s4,    b4, d4);
        bif[0] = bi; bif[1] = bf; dif[0] = di; dif[1] = df;
        bgo[0] = bg; bgo[1] = bo; dgo[0] = dg; dgo[1] = dq;
#pragma unroll
        for (int k = 0; k < 5; ++k) {
            wif[k][0] = NL2E  * W_hh[ri * 5 + k];
            wif[k][1] = NL2E  * W_hh[rf * 5 + k];
            wgo[k][0] = T2L2E * W_hh[rg * 5 + k];
            wgo[k][1] = NL2E  * W_hh[ro * 5 + k];
            w4[k]     = s4    * W_hh[r4 * 5 + k];
        }
    }

    float h0 = 0.f, h1 = 0.f, h2 = 0.f, h3 = 0.f, h4 = 0.f;
    float chat = 0.f, chat4 = 0.f;   // own unit / unit 4 (redundant per quad)

    auto step = [&](int xt) {
        const float xtf = (float)xt;
        v2f xv; xv[0] = xtf; xv[1] = xtf;
        v2f gif = __builtin_elementwise_fma(xv, dif, bif);
        v2f ggo = __builtin_elementwise_fma(xv, dgo, bgo);
        float g4 = fmaf(xtf, d4, b4);
        const float hk[5] = {h0, h1, h2, h3, h4};
#pragma unroll
        for (int k = 0; k < 5; ++k) {
            v2f hv; hv[0] = hk[k]; hv[1] = hk[k];
            gif = __builtin_elementwise_fma(wif[k], hv, gif);
            ggo = __builtin_elementwise_fma(wgo[k], hv, ggo);
            g4  = fmaf(w4[k], hk[k], g4);
        }

        // ---- 5 exps (v_exp_f32) ----
        float Ei = fexp2(gif[0]), Ef = fexp2(gif[1]);
        float Eg = fexp2(ggo[0]), Eo = fexp2(ggo[1]);
        float e4 = fexp2(g4);

        // ---- unit-4 gate gather: quad broadcasts (full-rate DPP) ----
        float Ei4 = qb<0x00>(e4);
        float Ef4 = qb<0x55>(e4);
        float Eg4 = qb<0xAA>(e4);
        float Eo4 = qb<0xFF>(e4);

        // ---- c-combine: own unit ----
        float Ai = 1.f + Ei, Af = 1.f + Ef, Ag = 1.f + Eg;
        float P  = Ai * Ag,  D  = P * Af;
        float t  = fmaf(T2L2E, Eg, -T2L2E);
        float N  = fmaf(chat, P, t * Af);
        // ---- c-combine: unit 4 (redundant across quad, identical values) ----
        float Ai4 = 1.f + Ei4, Af4 = 1.f + Ef4, Ag4 = 1.f + Eg4;
        float P4  = Ai4 * Ag4, D4  = P4 * Af4;
        float t4  = fmaf(T2L2E, Eg4, -T2L2E);
        float N4  = fmaf(chat4, P4, t4 * Af4);
        // ---- one shared rcp for both denominators ----
        float R = frcp(D * D4);
        chat  = (N  * D4) * R;
        chat4 = (N4 * D ) * R;

        // ---- h-phase ----
        float Ec  = fexp2(chat);
        float Ec4 = fexp2(chat4);
        float Dn  = (1.f + Eo ) * (1.f + Ec ), Tn  = Ec  - 1.f;
        float Dn4 = (1.f + Eo4) * (1.f + Ec4), Tn4 = Ec4 - 1.f;
        float S = frcp(Dn * Dn4);
        float hown = (Tn * Dn4) * S;
        h4 = (Tn4 * Dn) * S;

        // ---- h broadcast for next matvec ----
        h0 = qb<0x00>(hown);
        h1 = qb<0x55>(hown);
        h2 = qb<0xAA>(hown);
        h3 = qb<0xFF>(hown);
    };

    // ---- main scan: 64 int4 loads, prefetch-next, 4 steps per iter ----
    // (the 4 lanes of a quad load identical addresses -> one transaction)
    const int4* xr = reinterpret_cast<const int4*>(x + (size_t)seq * TT);
    int4 cur = xr[0];
#pragma unroll 1
    for (int it = 0; it < TT / 4 - 1; ++it) {
        int4 nxt = xr[it + 1];
        step(cur.x); step(cur.y); step(cur.z); step(cur.w);
        cur = nxt;
    }
    step(cur.x); step(cur.y); step(cur.z); step(cur.w);

    // ---- linear head: lane role==0 of each quad has h0..h3 (bcast) + h4 ----
    if (role == 0) {
        const float hfin[5] = {h0, h1, h2, h3, h4};
        float o0 = b_lin[0], o1 = b_lin[1];
#pragma unroll
        for (int j = 0; j < 5; ++j) {
            o0 = fmaf(W_lin[j],     hfin[j], o0);
            o1 = fmaf(W_lin[5 + j], hfin[j], o1);
        }
        reinterpret_cast<float2*>(out)[seq] = make_float2(o0, o1);
    }
}

extern "C" void kernel_launch(void* const* d_in, const int* in_sizes, int n_in,
                              void* d_out, int out_size, void* d_ws, size_t ws_size,
                              hipStream_t stream) {
    const int* x        = (const int*)d_in[0];
    const float* emb    = (const float*)d_in[1];
    const float* W_ih   = (const float*)d_in[2];
    const float* W_hh   = (const float*)d_in[3];
    const float* b_ih   = (const float*)d_in[4];
    const float* b_hh   = (const float*)d_in[5];
    const float* W_lin  = (const float*)d_in[6];
    const float* b_lin  = (const float*)d_in[7];
    float* out          = (float*)d_out;

    const int B = in_sizes[0] / TT;       // 65536
    const int threads = B * 4;            // 4 lanes per sequence
    const int block = 256;
    const int grid = threads / block;     // 1024 blocks = 4096 waves = 4/SIMD

    lstm_q4<<<grid, block, 0, stream>>>(x, emb, W_ih, W_hh, b_ih, b_hh,
                                        W_lin, b_lin, out);
}

// Round 12
// 103.816 us; speedup vs baseline: 1.5003x; 1.2611x over previous
//
#include <hip/hip_runtime.h>

// LSTM: B=65536 seqs, T=256, E=H=5, x in {0,1}.
// TWO lanes per sequence, UNIT-level split: even lane owns units {0,1},
// odd owns {2,3}; unit 4's four gates split 2/2 (even: i4,f4; odd: g4,o4)
// and unit-4 combine computed redundantly per lane (identical inputs).
// 131072 threads = 2048 waves = 2 waves/SIMD: R11 proved co-resident waves
// hide the ~400cyc/step stall pool; this split keeps per-lane work packed:
//  - own-unit combine stays v2f-packed (2 units = 1 pair, R7's exact shape)
//  - weight columns gathered in LOCAL h order [own0,own1,recv0,recv1,u4]
//    so the h exchange is 2 pswaps, ZERO cndmasks (R5's bloat killer).
// Trans issue conserved: 13 exp + 4 rcp per lane-step (26 exp/seq vs 25).
// Math identical to R7 (validated):
//   c' = [chat*Ai*Ag + 2log2e*(Eg-1)*Af]/(Ai*Af*Ag),  A* = 1+E*
//   h  = (Ec-1)/((1+Eo)(1+Ec));  chat = 2log2e*c;  rcp pair-grouped.

typedef float v2f __attribute__((ext_vector_type(2)));

constexpr int TT = 256;

__device__ __forceinline__ float fexp2(float v) { return __builtin_amdgcn_exp2f(v); }
__device__ __forceinline__ float frcp(float v)  { return __builtin_amdgcn_rcpf(v); }
// swap with neighbor lane (lane^1) via DPP quad_perm [1,0,3,2]
__device__ __forceinline__ float pswap(float v) {
    return __builtin_bit_cast(float, __builtin_amdgcn_mov_dpp(
        __builtin_bit_cast(int, v), 0xB1, 0xF, 0xF, true));
}

__global__ __launch_bounds__(256)
__attribute__((amdgpu_waves_per_eu(2)))
void lstm_u2(
    const int* __restrict__ x,       // [B, T]
    const float* __restrict__ emb,   // [2, E]
    const float* __restrict__ W_ih,  // [4H, E]
    const float* __restrict__ W_hh,  // [4H, H]
    const float* __restrict__ b_ih,  // [4H]
    const float* __restrict__ b_hh,  // [4H]
    const float* __restrict__ W_lin, // [2, H]
    const float* __restrict__ b_lin, // [2]
    float* __restrict__ out)         // [B, 2]
{
    const int tid  = blockIdx.x * blockDim.x + threadIdx.x;
    const int seq  = tid >> 1;
    const int role = tid & 1;

    const float NL2E  = -1.4426950408889634f;  // -log2(e)   (sigmoid rows)
    const float T2L2E =  2.8853900817779268f;  // 2*log2(e)  (tanh row)
    const v2f ONE = {1.f, 1.f};
    const v2f T2v = {T2L2E, T2L2E};

    const int ua = 2 * role, ub = 2 * role + 1;
    // local h order: [own_a, own_b, other_a, other_b, unit4]
    const int lu[5] = {ua, ub, 2 - 2 * role, 3 - 2 * role, 4};
    // unit-4 gate rows this lane computes: role0 -> {i4,f4} rows {4,9};
    // role1 -> {g4,o4} rows {14,19}
    const int  r4a = role ? 14 : 4,  r4b = role ? 19 : 9;
    const float s4a = role ? T2L2E : NL2E;   // row 14 is the tanh row
    const float s4b = NL2E;

    // per-gate base/delta (x=0 value, x=1 delta), pre-scaled
    auto prep = [&](int r, float s, float& base, float& delta) {
        float g0 = b_ih[r] + b_hh[r], g1 = g0;
#pragma unroll
        for (int e = 0; e < 5; ++e) {
            float w = W_ih[r * 5 + e];
            g0 = fmaf(w, emb[e],     g0);
            g1 = fmaf(w, emb[5 + e], g1);
        }
        base  = s * g0;
        delta = s * (g1 - g0);
    };

    v2f wI[5], wF[5], wG[5], wO[5], w4[5];       // matvec weights, local order
    v2f bI, bF, bG, bO, b4, dI, dF, dG, dO, d4;
    {
        float t0, t1;
        prep(ua,      NL2E,  t0, t1); bI[0] = t0; dI[0] = t1;
        prep(ub,      NL2E,  t0, t1); bI[1] = t0; dI[1] = t1;
        prep(5 + ua,  NL2E,  t0, t1); bF[0] = t0; dF[0] = t1;
        prep(5 + ub,  NL2E,  t0, t1); bF[1] = t0; dF[1] = t1;
        prep(10 + ua, T2L2E, t0, t1); bG[0] = t0; dG[0] = t1;
        prep(10 + ub, T2L2E, t0, t1); bG[1] = t0; dG[1] = t1;
        prep(15 + ua, NL2E,  t0, t1); bO[0] = t0; dO[0] = t1;
        prep(15 + ub, NL2E,  t0, t1); bO[1] = t0; dO[1] = t1;
        prep(r4a,     s4a,   t0, t1); b4[0] = t0; d4[0] = t1;
        prep(r4b,     s4b,   t0, t1); b4[1] = t0; d4[1] = t1;
#pragma unroll
        for (int k = 0; k < 5; ++k) {
            const int c = lu[k];
            float a, b2, c2, d2, e2, f2, g2, h2, p2, q2;
            a  = NL2E  * W_hh[ua * 5 + c];        b2 = NL2E  * W_hh[ub * 5 + c];
            c2 = NL2E  * W_hh[(5 + ua) * 5 + c];  d2 = NL2E  * W_hh[(5 + ub) * 5 + c];
            e2 = T2L2E * W_hh[(10 + ua) * 5 + c]; f2 = T2L2E * W_hh[(10 + ub) * 5 + c];
            g2 = NL2E  * W_hh[(15 + ua) * 5 + c]; h2 = NL2E  * W_hh[(15 + ub) * 5 + c];
            p2 = s4a   * W_hh[r4a * 5 + c];       q2 = s4b   * W_hh[r4b * 5 + c];
            asm volatile("" : "+v"(a), "+v"(b2), "+v"(c2), "+v"(d2), "+v"(e2),
                             "+v"(f2), "+v"(g2), "+v"(h2), "+v"(p2), "+v"(q2));
            wI[k][0] = a;  wI[k][1] = b2;
            wF[k][0] = c2; wF[k][1] = d2;
            wG[k][0] = e2; wG[k][1] = f2;
            wO[k][0] = g2; wO[k][1] = h2;
            w4[k][0] = p2; w4[k][1] = q2;
        }
    }

    v2f  chat = {0.f, 0.f};      // own units (ua, ub)
    float chat4 = 0.f;           // unit 4 (redundant per pair)
    float hL[5] = {0.f, 0.f, 0.f, 0.f, 0.f};   // local order

    auto step = [&](int xt) {
        const float xtf = (float)xt;
        v2f xv; xv[0] = xtf; xv[1] = xtf;
        v2f gI = __builtin_elementwise_fma(xv, dI, bI);
        v2f gF = __builtin_elementwise_fma(xv, dF, bF);
        v2f gG = __builtin_elementwise_fma(xv, dG, bG);
        v2f gO = __builtin_elementwise_fma(xv, dO, bO);
        v2f g4 = __builtin_elementwise_fma(xv, d4, b4);
#pragma unroll
        for (int k = 0; k < 5; ++k) {
            v2f hv; hv[0] = hL[k]; hv[1] = hL[k];
            gI = __builtin_elementwise_fma(wI[k], hv, gI);
            gF = __builtin_elementwise_fma(wF[k], hv, gF);
            gG = __builtin_elementwise_fma(wG[k], hv, gG);
            gO = __builtin_elementwise_fma(wO[k], hv, gO);
            g4 = __builtin_elementwise_fma(w4[k], hv, g4);
        }

        // ---- 10 gate exps ----
        v2f Ei; Ei[0] = fexp2(gI[0]); Ei[1] = fexp2(gI[1]);
        v2f Ef; Ef[0] = fexp2(gF[0]); Ef[1] = fexp2(gF[1]);
        v2f Eg; Eg[0] = fexp2(gG[0]); Eg[1] = fexp2(gG[1]);
        v2f Eo; Eo[0] = fexp2(gO[0]); Eo[1] = fexp2(gO[1]);
        float m0 = fexp2(g4[0]), m1 = fexp2(g4[1]);

        // ---- unit-4 E exchange (2 DPP) + named assembly (4 cndmask) ----
        float r0 = pswap(m0), r1 = pswap(m1);
        float Ei4 = role ? r0 : m0;
        float Ef4 = role ? r1 : m1;
        float Eg4 = role ? m0 : r0;
        float Eo4 = role ? m1 : r1;

        // ---- c-combine: own pair (packed) ----
        v2f Ai = Ei + ONE, Af = Ef + ONE, Ag = Eg + ONE;
        v2f P = Ai * Ag, D = P * Af;
        v2f t = __builtin_elementwise_fma(T2v, Eg, -T2v);
        v2f N = __builtin_elementwise_fma(chat, P, t * Af);
        // ---- c-combine: unit 4 (scalar, redundant) ----
        float Ai4 = 1.f + Ei4, Af4 = 1.f + Ef4, Ag4 = 1.f + Eg4;
        float P4 = Ai4 * Ag4, D4 = P4 * Af4;
        float t4 = fmaf(T2L2E, Eg4, -T2L2E);
        float N4 = fmaf(chat4, P4, t4 * Af4);
        // ---- rcps ----
        {
            float R = frcp(D[0] * D[1]);
            v2f Rv; Rv[0] = R; Rv[1] = R;
            chat = (N * __builtin_shufflevector(D, D, 1, 0)) * Rv;
            chat4 = N4 * frcp(D4);
        }

        // ---- h-phase ----
        v2f Ec; Ec[0] = fexp2(chat[0]); Ec[1] = fexp2(chat[1]);
        float Ec4 = fexp2(chat4);
        v2f Dn = (Eo + ONE) * (Ec + ONE), Tn = Ec - ONE;
        float Dn4 = (1.f + Eo4) * (1.f + Ec4), Tn4 = Ec4 - 1.f;
        v2f hown;
        {
            float S = frcp(Dn[0] * Dn[1]);
            v2f Sv; Sv[0] = S; Sv[1] = S;
            hown = (Tn * __builtin_shufflevector(Dn, Dn, 1, 0)) * Sv;
            hL[4] = Tn4 * frcp(Dn4);
        }
        // ---- h exchange (2 DPP, zero cndmask thanks to local order) ----
        hL[0] = hown[0];
        hL[1] = hown[1];
        hL[2] = pswap(hown[0]);
        hL[3] = pswap(hown[1]);
    };

    // ---- main scan: 64 int4 loads, prefetch-next, 4 steps per iter ----
    // (both lanes of a pair load identical addresses -> shared transaction)
    const int4* xr = reinterpret_cast<const int4*>(x + (size_t)seq * TT);
    int4 cur = xr[0];
#pragma unroll 1
    for (int it = 0; it < TT / 4 - 1; ++it) {
        int4 nxt = xr[it + 1];
        step(cur.x); step(cur.y); step(cur.z); step(cur.w);
        cur = nxt;
    }
    step(cur.x); step(cur.y); step(cur.z); step(cur.w);

    // ---- linear head: role0's local order IS unit order [0,1,2,3,4] ----
    if (role == 0) {
        float o0 = b_lin[0], o1 = b_lin[1];
#pragma unroll
        for (int j = 0; j < 5; ++j) {
            o0 = fmaf(W_lin[j],     hL[j], o0);
            o1 = fmaf(W_lin[5 + j], hL[j], o1);
        }
        reinterpret_cast<float2*>(out)[seq] = make_float2(o0, o1);
    }
}

extern "C" void kernel_launch(void* const* d_in, const int* in_sizes, int n_in,
                              void* d_out, int out_size, void* d_ws, size_t ws_size,
                              hipStream_t stream) {
    const int* x        = (const int*)d_in[0];
    const float* emb    = (const float*)d_in[1];
    const float* W_ih   = (const float*)d_in[2];
    const float* W_hh   = (const float*)d_in[3];
    const float* b_ih   = (const float*)d_in[4];
    const float* b_hh   = (const float*)d_in[5];
    const float* W_lin  = (const float*)d_in[6];
    const float* b_lin  = (const float*)d_in[7];
    float* out          = (float*)d_out;

    const int B = in_sizes[0] / TT;       // 65536
    const int threads = B * 2;            // 2 lanes per sequence
    const int block = 256;
    const int grid = threads / block;     // 512 blocks = 2048 waves = 2/SIMD

    lstm_u2<<<grid, block, 0, stream>>>(x, emb, W_ih, W_hh, b_ih, b_hh,
                                        W_lin, b_lin, out);
}

// Round 13
// 92.977 us; speedup vs baseline: 1.6752x; 1.1166x over previous
//
#include <hip/hip_runtime.h>

// LSTM: B=65536 seqs, T=256, E=H=5, x in {0,1}. One thread per sequence.
// Final model (R3..R12 measured): waves/SIMD = lanes/seq; trans+VALU share
// one in-order issue port; issue floor = 711 cyc/step (25 v_exp + 6 v_rcp
// = 496 + ~215 full-rate). L=1 wall 873 = 711 + 162 spine stall. Splits
// cost more issue than they hide (L=2: +173/-73; L=4: +500/-146).
// R13 = R7 math, hand-scheduled to fill the 4 spine-latency windows:
//   c-phase:  D's -> 3 rcps -> [shadow: E6/E7 exps, N's] -> applies
//   Ec-phase: 5 exps -> [shadow: NEXT step's g-init (g buffer dead), Eo+1]
//   h-phase:  Dn's -> 3 rcps -> [shadow: Tn's] -> applies
// Math identical to R7 (passed, absmax 4.9e-4):
//   c' = [chat*Ai*Ag + 2log2e*(Eg-1)*Af]/(Ai*Af*Ag),  A* = 1+E*
//   h  = (Ec-1)/((1+Eo)(1+Ec));  chat = 2log2e*c;  rcp pair-grouped.
// Gate-pair layout: p0..7: row=(p>>1)*5+(p&1)*2+h ->
//   (i0,i1)(i2,i3)(f0,f1)(f2,f3)(g0,g1)(g2,g3)(o0,o1)(o2,o3)
//   p8:(i4,f4)=rows{4,9}; p9:(g4,o4)=rows{14,19}

typedef float v2f __attribute__((ext_vector_type(2)));

constexpr int TT = 256;

__device__ __forceinline__ float fexp2(float v) { return __builtin_amdgcn_exp2f(v); }
__device__ __forceinline__ float frcp(float v)  { return __builtin_amdgcn_rcpf(v); }

__device__ __forceinline__ int pair_row(int p, int h) {
    if (p < 8) return (p >> 1) * 5 + (p & 1) * 2 + h;
    return (p == 8) ? (h ? 9 : 4) : (h ? 19 : 14);
}

// pack two uniform floats into a uniform 64-bit value (SGPR pair residency)
__device__ __forceinline__ double upack(float w0, float w1) {
    unsigned lo = (unsigned)__builtin_amdgcn_readfirstlane(__builtin_bit_cast(int, w0));
    unsigned hi = (unsigned)__builtin_amdgcn_readfirstlane(__builtin_bit_cast(int, w1));
    unsigned long long u = ((unsigned long long)hi << 32) | lo;
    return __builtin_bit_cast(double, u);
}

__global__ __launch_bounds__(256)
__attribute__((amdgpu_waves_per_eu(1, 1)))
void lstm_fused(
    const int* __restrict__ x,       // [B, T]
    const float* __restrict__ emb,   // [2, E]
    const float* __restrict__ W_ih,  // [4H, E]
    const float* __restrict__ W_hh,  // [4H, H]
    const float* __restrict__ b_ih,  // [4H]
    const float* __restrict__ b_hh,  // [4H]
    const float* __restrict__ W_lin, // [2, H]
    const float* __restrict__ b_lin, // [2]
    float* __restrict__ out)         // [B, 2]
{
    const int b = blockIdx.x * blockDim.x + threadIdx.x;

    const float NL2E  = -1.4426950408889634f;  // -log2(e)   (sigmoid rows)
    const float T2L2E =  2.8853900817779268f;  // 2*log2(e)  (tanh rows)
    const v2f ONE = {1.f, 1.f};
    const v2f T2v = {T2L2E, T2L2E};

    // ---- setup (identical to R7) ----
    double wu[4][10];   // matvec weights k=0..3, uniform -> SGPR pairs
    v2f    wv[10];      // matvec weights k=4, pinned VGPR
    v2f bpk[10], dpk[10];
#pragma unroll
    for (int p = 0; p < 10; ++p) {
        float v0[2], v1[2], w4[2];
        float wk[4][2];
#pragma unroll
        for (int h = 0; h < 2; ++h) {
            const int r = pair_row(p, h);
            const float s = (r >= 10 && r < 15) ? T2L2E : NL2E;
            float g0 = b_ih[r] + b_hh[r], g1 = g0;
#pragma unroll
            for (int e = 0; e < 5; ++e) {
                float w = W_ih[r * 5 + e];
                g0 = fmaf(w, emb[e],     g0);
                g1 = fmaf(w, emb[5 + e], g1);
            }
            v0[h] = s * g0;
            v1[h] = s * (g1 - g0);
#pragma unroll
            for (int k = 0; k < 4; ++k) wk[k][h] = s * W_hh[r * 5 + k];
            w4[h] = s * W_hh[r * 5 + 4];
        }
#pragma unroll
        for (int k = 0; k < 4; ++k) wu[k][p] = upack(wk[k][0], wk[k][1]);
        asm volatile("" : "+v"(w4[0]), "+v"(w4[1]));
        wv[p][0] = w4[0]; wv[p][1] = w4[1];
        asm volatile("" : "+v"(v0[0]), "+v"(v0[1]), "+v"(v1[0]), "+v"(v1[1]));
        bpk[p][0] = v0[0]; bpk[p][1] = v0[1];
        dpk[p][0] = v1[0]; dpk[p][1] = v1[1];
    }

    v2f chat01 = {0.f, 0.f}, chat23 = {0.f, 0.f};
    float chat4 = 0.f;
    v2f h01 = {0.f, 0.f}, h23 = {0.f, 0.f};
    float h4 = 0.f;

    v2f g[10];   // carried gate accumulator (pre-initialized for next step)

    // step: consumes g (pre-initialized with base + x_cur*delta), updates
    // h/chat state, and RE-INITIALIZES g for x_next inside the Ec shadow.
    auto step = [&](float xnf) {
        // ---- recurrent matvec: k=0..3 from SGPR pairs, k=4 from VGPR ----
        const float hk[4] = {h01[0], h01[1], h23[0], h23[1]};
#pragma unroll
        for (int k = 0; k < 4; ++k) {
            v2f hv; hv[0] = hk[k]; hv[1] = hk[k];
#pragma unroll
            for (int p = 0; p < 10; ++p) {
                v2f w = __builtin_bit_cast(v2f, wu[k][p]);
                g[p] = __builtin_elementwise_fma(w, hv, g[p]);
            }
        }
        {
            v2f hv; hv[0] = h4; hv[1] = h4;
#pragma unroll
            for (int p = 0; p < 10; ++p)
                g[p] = __builtin_elementwise_fma(wv[p], hv, g[p]);
        }

        // ---- 16 exps: i,f,g gates + unit-4 pairs ----
        v2f E0, E1, E2, E3, E4, E5, E8, E9;
        E0[0] = fexp2(g[0][0]); E0[1] = fexp2(g[0][1]);   // Ei01
        E1[0] = fexp2(g[1][0]); E1[1] = fexp2(g[1][1]);   // Ei23
        E2[0] = fexp2(g[2][0]); E2[1] = fexp2(g[2][1]);   // Ef01
        E3[0] = fexp2(g[3][0]); E3[1] = fexp2(g[3][1]);   // Ef23
        E4[0] = fexp2(g[4][0]); E4[1] = fexp2(g[4][1]);   // Eg01
        E5[0] = fexp2(g[5][0]); E5[1] = fexp2(g[5][1]);   // Eg23
        E8[0] = fexp2(g[8][0]); E8[1] = fexp2(g[8][1]);   // (Ei4,Ef4)
        E9[0] = fexp2(g[9][0]); E9[1] = fexp2(g[9][1]);   // (Eg4,Eo4)

        // ---- denominators FIRST ----
        v2f Ai01 = E0 + ONE, Af01 = E2 + ONE, Ag01 = E4 + ONE;
        v2f P01 = Ai01 * Ag01, D01 = P01 * Af01;
        v2f Ai23 = E1 + ONE, Af23 = E3 + ONE, Ag23 = E5 + ONE;
        v2f P23 = Ai23 * Ag23, D23 = P23 * Af23;
        v2f AiAf4 = E8 + ONE;   // (Ai4, Af4)
        v2f AgAo4 = E9 + ONE;   // (Ag4, Ao4)
        float P4 = AiAf4[0] * AgAo4[0];
        float D4 = P4 * AiAf4[1];

        // ---- issue all 3 c-rcps ----
        float R01 = frcp(D01[0] * D01[1]);
        float R23 = frcp(D23[0] * D23[1]);
        float R4g = frcp(D4);

        // ---- rcp shadow: o-gate exps + numerators ----
        v2f E6, E7;
        E6[0] = fexp2(g[6][0]); E6[1] = fexp2(g[6][1]);   // Eo01
        E7[0] = fexp2(g[7][0]); E7[1] = fexp2(g[7][1]);   // Eo23
        v2f t01 = __builtin_elementwise_fma(T2v, E4, -T2v);
        v2f N01 = __builtin_elementwise_fma(chat01, P01, t01 * Af01);
        v2f t23 = __builtin_elementwise_fma(T2v, E5, -T2v);
        v2f N23 = __builtin_elementwise_fma(chat23, P23, t23 * Af23);
        float t4 = fmaf(T2L2E, E9[0], -T2L2E);
        float N4 = fmaf(chat4, P4, t4 * AiAf4[1]);

        // ---- apply ----
        {
            v2f Rv01; Rv01[0] = R01; Rv01[1] = R01;
            chat01 = (N01 * __builtin_shufflevector(D01, D01, 1, 0)) * Rv01;
            v2f Rv23; Rv23[0] = R23; Rv23[1] = R23;
            chat23 = (N23 * __builtin_shufflevector(D23, D23, 1, 0)) * Rv23;
            chat4 = N4 * R4g;
        }

        // ---- issue 5 Ec exps ----
        v2f Ec01; Ec01[0] = fexp2(chat01[0]); Ec01[1] = fexp2(chat01[1]);
        v2f Ec23; Ec23[0] = fexp2(chat23[0]); Ec23[1] = fexp2(chat23[1]);
        float Ec4 = fexp2(chat4);

        // ---- Ec shadow: NEXT step's g-init (g is dead) + Eo+1 ----
        {
            v2f xv; xv[0] = xnf; xv[1] = xnf;
#pragma unroll
            for (int p = 0; p < 10; ++p)
                g[p] = __builtin_elementwise_fma(xv, dpk[p], bpk[p]);
        }
        v2f EoP01 = E6 + ONE, EoP23 = E7 + ONE;
        float EoP4 = AgAo4[1];

        // ---- h denominators, issue 3 rcps ----
        v2f Dn01 = EoP01 * (Ec01 + ONE);
        v2f Dn23 = EoP23 * (Ec23 + ONE);
        float Dn4 = EoP4 * (Ec4 + 1.f);
        float S01 = frcp(Dn01[0] * Dn01[1]);
        float S23 = frcp(Dn23[0] * Dn23[1]);
        float S4  = frcp(Dn4);

        // ---- rcp shadow: Tn ----
        v2f Tn01 = Ec01 - ONE, Tn23 = Ec23 - ONE;
        float Tn4 = Ec4 - 1.f;

        // ---- apply ----
        {
            v2f Sv01; Sv01[0] = S01; Sv01[1] = S01;
            h01 = (Tn01 * __builtin_shufflevector(Dn01, Dn01, 1, 0)) * Sv01;
            v2f Sv23; Sv23[0] = S23; Sv23[1] = S23;
            h23 = (Tn23 * __builtin_shufflevector(Dn23, Dn23, 1, 0)) * Sv23;
            h4 = Tn4 * S4;
        }
    };

    // ---- main scan: 64 int4 loads, g software-pipelined across steps ----
    const int4* xr = reinterpret_cast<const int4*>(x + (size_t)b * TT);
    int4 cur = xr[0];
    {   // prologue: g for step 0
        float xf = (float)cur.x;
        v2f xv; xv[0] = xf; xv[1] = xf;
#pragma unroll
        for (int p = 0; p < 10; ++p)
            g[p] = __builtin_elementwise_fma(xv, dpk[p], bpk[p]);
    }
#pragma unroll 1
    for (int it = 0; it < TT / 4 - 1; ++it) {
        int4 nxt = xr[it + 1];
        step((float)cur.y);
        step((float)cur.z);
        step((float)cur.w);
        step((float)nxt.x);
        cur = nxt;
    }
    step((float)cur.y);
    step((float)cur.z);
    step((float)cur.w);
    step(0.f);               // last step; its g-reinit is dead

    // ---- linear head ----
    const float hfin[5] = {h01[0], h01[1], h23[0], h23[1], h4};
    float o0 = b_lin[0], o1 = b_lin[1];
#pragma unroll
    for (int j = 0; j < 5; ++j) {
        o0 = fmaf(W_lin[j],     hfin[j], o0);
        o1 = fmaf(W_lin[5 + j], hfin[j], o1);
    }
    reinterpret_cast<float2*>(out)[b] = make_float2(o0, o1);
}

extern "C" void kernel_launch(void* const* d_in, const int* in_sizes, int n_in,
                              void* d_out, int out_size, void* d_ws, size_t ws_size,
                              hipStream_t stream) {
    const int* x        = (const int*)d_in[0];
    const float* emb    = (const float*)d_in[1];
    const float* W_ih   = (const float*)d_in[2];
    const float* W_hh   = (const float*)d_in[3];
    const float* b_ih   = (const float*)d_in[4];
    const float* b_hh   = (const float*)d_in[5];
    const float* W_lin  = (const float*)d_in[6];
    const float* b_lin  = (const float*)d_in[7];
    float* out          = (float*)d_out;

    const int B = in_sizes[0] / TT;   // 65536
    const int block = 256;
    const int grid = B / block;       // 256 blocks -> 1024 waves -> 1/SIMD

    lstm_fused<<<grid, block, 0, stream>>>(x, emb, W_ih, W_hh, b_ih, b_hh,
                                           W_lin, b_lin, out);
}